// Round 8
// baseline (285.332 us; speedup 1.0000x reference)
//
#include <hip/hip_runtime.h>
#include <hip/hip_cooperative_groups.h>

namespace cg = cooperative_groups;

#define N_FEATURES 4096
#define N_GROUPS   1024
#define BATCH      8192

typedef float f32x4 __attribute__((ext_vector_type(4)));

// ---------------- Cooperative fused path ----------------
// 512 blocks x 256 threads (2 blocks/CU -- big margin for the cooperative
// occupancy validator). Each wave owns 4 rows.
// Phase A: block 0 builds coeff in LDS and publishes it with AGENT-scope
//   atomic stores (device-coherent, bypasses per-XCD L2 staleness);
//   all other blocks issue the 16 nt loads of their first row so the build
//   hides under the load issue.
// grid.sync(), then every wave pulls coeff into 64 registers (builder from
// LDS; others via AGENT-scope atomic loads -- coherent by construction),
// and streams its 4 rows with nontemporal x loads (round-6 verified win).
__global__ __launch_bounds__(256, 2) void fused_coop(
    const float* __restrict__ x,
    const int*   __restrict__ flat_idx,
    const int*   __restrict__ seg_ids,
    const float* __restrict__ w_flat,
    const float* __restrict__ diag_w,
    const float* __restrict__ dense_W,
    float* __restrict__ coeff,
    float* __restrict__ out,
    int total)
{
    const int lane = threadIdx.x & 63;
    const int wid  = threadIdx.x >> 6;
    const int wave = (blockIdx.x << 2) | wid;     // 0..2047
    const int row0 = wave << 2;                   // 4 rows per wave

    __shared__ float s_coeff[N_FEATURES];
    f32x4 a[16];
    const bool builder = (blockIdx.x == 0);

    if (builder) {
        for (int i = threadIdx.x; i < N_FEATURES; i += 256) s_coeff[i] = 0.0f;
        __syncthreads();
#pragma unroll
        for (int k = 0; k < 20; ++k) {            // 20*256 = 5120 >= total = 5115
            const int i = k * 256 + (int)threadIdx.x;
            const bool valid = (i < total);
            const int  idx = valid ? flat_idx[i] : 0;
            const int  g   = valid ? seg_ids[i]  : 0;
            const float wv = valid ? w_flat[i]   : 0.0f;
            const float c  = wv * diag_w[g] * dense_W[g];
            if (valid) atomicAdd(&s_coeff[idx], c);
        }
        for (int i = 20 * 256 + (int)threadIdx.x; i < total; i += 256) {  // robustness tail
            const int g = seg_ids[i];
            atomicAdd(&s_coeff[flat_idx[i]], w_flat[i] * diag_w[g] * dense_W[g]);
        }
        __syncthreads();
        // Publish device-coherent: agent-scope stores cannot be served stale
        // from another XCD's L2 on the read side.
        for (int i = threadIdx.x; i < N_FEATURES; i += 256)
            __hip_atomic_store(&coeff[i], s_coeff[i],
                               __ATOMIC_RELAXED, __HIP_MEMORY_SCOPE_AGENT);
    } else {
        const f32x4* __restrict__ xr0 = (const f32x4*)(x + (size_t)row0 * N_FEATURES);
#pragma unroll
        for (int k = 0; k < 16; ++k)
            a[k] = __builtin_nontemporal_load(&xr0[(k << 6) | lane]);
    }

    cg::this_grid().sync();                        // ordering for coeff publish

    // coeff -> 64 registers per lane (element (k<<6)|lane matches x layout).
    float c[64];
    if (builder) {
#pragma unroll
        for (int k = 0; k < 16; ++k) {
            const f32x4 cv = ((const f32x4*)s_coeff)[(k << 6) | lane];
            c[4*k+0] = cv.x; c[4*k+1] = cv.y; c[4*k+2] = cv.z; c[4*k+3] = cv.w;
        }
    } else {
#pragma unroll
        for (int k = 0; k < 16; ++k) {
            const int base = ((k << 6) | lane) << 2;
#pragma unroll
            for (int j = 0; j < 4; ++j)
                c[4*k+j] = __hip_atomic_load(&coeff[base + j],
                                             __ATOMIC_RELAXED, __HIP_MEMORY_SCOPE_AGENT);
        }
    }

#pragma unroll
    for (int r = 0; r < 4; ++r) {
        const int row = row0 + r;
        const f32x4* __restrict__ xr = (const f32x4*)(x + (size_t)row * N_FEATURES);
        float acc = 0.0f;
        if (r == 0 && !builder) {                  // block-uniform branch
#pragma unroll
            for (int k = 0; k < 16; ++k)
                acc += a[k].x * c[4*k+0] + a[k].y * c[4*k+1]
                     + a[k].z * c[4*k+2] + a[k].w * c[4*k+3];
        } else {
#pragma unroll
            for (int k = 0; k < 16; ++k) {
                const f32x4 xv = __builtin_nontemporal_load(&xr[(k << 6) | lane]);
                acc += xv.x * c[4*k+0] + xv.y * c[4*k+1]
                     + xv.z * c[4*k+2] + xv.w * c[4*k+3];
            }
        }
#pragma unroll
        for (int off = 32; off > 0; off >>= 1)
            acc += __shfl_down(acc, off, 64);
        if (lane == 0) out[row] = acc;
    }
}

// ---------------- Fallback: verified round-6 two-kernel path ----------------
__global__ __launch_bounds__(1024) void build_coeff_kernel(
    const int* __restrict__ flat_idx,
    const int* __restrict__ seg_ids,
    const float* __restrict__ w_flat,
    const float* __restrict__ diag_w,
    const float* __restrict__ dense_W,
    float* __restrict__ coeff,
    int total)
{
    __shared__ float s_coeff[N_FEATURES];
    for (int i = threadIdx.x; i < N_FEATURES; i += 1024) s_coeff[i] = 0.0f;
    __syncthreads();
#pragma unroll
    for (int k = 0; k < 5; ++k) {
        const int i = k * 1024 + (int)threadIdx.x;
        const bool valid = (i < total);
        const int  idx = valid ? flat_idx[i] : 0;
        const int  g   = valid ? seg_ids[i]  : 0;
        const float wv = valid ? w_flat[i]   : 0.0f;
        const float c  = wv * diag_w[g] * dense_W[g];
        if (valid) atomicAdd(&s_coeff[idx], c);
    }
    for (int i = 5 * 1024 + (int)threadIdx.x; i < total; i += 1024) {
        const int g = seg_ids[i];
        atomicAdd(&s_coeff[flat_idx[i]], w_flat[i] * diag_w[g] * dense_W[g]);
    }
    __syncthreads();
    for (int i = threadIdx.x; i < N_FEATURES; i += 1024) coeff[i] = s_coeff[i];
}

__global__ __launch_bounds__(256) void gemv_kernel(
    const float* __restrict__ x,
    const float* __restrict__ coeff,
    float* __restrict__ out)
{
    const int wid  = threadIdx.x >> 6;
    const int lane = threadIdx.x & 63;
    const int row  = (blockIdx.x << 2) | wid;

    const f32x4* __restrict__ xr = (const f32x4*)(x + (size_t)row * N_FEATURES);
    const f32x4* __restrict__ c4 = (const f32x4*)coeff;

    float acc = 0.0f;
#pragma unroll
    for (int k = 0; k < 16; ++k) {
        const int i = (k << 6) | lane;
        const f32x4 xv = __builtin_nontemporal_load(&xr[i]);
        const f32x4 cv = c4[i];
        acc += xv.x * cv.x + xv.y * cv.y + xv.z * cv.z + xv.w * cv.w;
    }
#pragma unroll
    for (int off = 32; off > 0; off >>= 1)
        acc += __shfl_down(acc, off, 64);
    if (lane == 0) out[row] = acc;
}

extern "C" void kernel_launch(void* const* d_in, const int* in_sizes, int n_in,
                              void* d_out, int out_size, void* d_ws, size_t ws_size,
                              hipStream_t stream) {
    const float* x        = (const float*)d_in[0];  // [BATCH, N_FEATURES]
    const int*   flat_idx = (const int*)d_in[1];    // [total]
    const int*   seg_ids  = (const int*)d_in[2];    // [total]
    const float* w_flat   = (const float*)d_in[3];  // [total]
    const float* diag_w   = (const float*)d_in[4];  // [N_GROUPS]
    const float* dense_W  = (const float*)d_in[5];  // [N_GROUPS]
    float* out   = (float*)d_out;                   // [BATCH] (shape [BATCH,1])
    float* coeff = (float*)d_ws;                    // N_FEATURES floats
    int total = in_sizes[1];

    void* args[] = { (void*)&x, (void*)&flat_idx, (void*)&seg_ids, (void*)&w_flat,
                     (void*)&diag_w, (void*)&dense_W, (void*)&coeff, (void*)&out,
                     (void*)&total };
    hipError_t err = hipLaunchCooperativeKernel((const void*)fused_coop,
                                                dim3(512), dim3(256), args, 0, stream);
    if (err != hipSuccess) {
        // Cooperative launch rejected (occupancy validator / capture mode):
        // fall back to the verified round-6 two-kernel path.
        build_coeff_kernel<<<1, 1024, 0, stream>>>(flat_idx, seg_ids, w_flat,
                                                   diag_w, dense_W, coeff, total);
        gemv_kernel<<<BATCH / 4, 256, 0, stream>>>(x, coeff, out);
    }
}

// Round 9
// 200.193 us; speedup vs baseline: 1.4253x; 1.4253x over previous
//
#include <hip/hip_runtime.h>

#define N_FEATURES 4096
#define N_GROUPS   1024
#define BATCH      8192

typedef float f32x4 __attribute__((ext_vector_type(4)));

// Kernel 1 (verified round-6): coeff[f] = sum_{i: flat_idx[i]==f}
//   w_flat[i]*diag_w[seg_ids[i]]*dense_W[seg_ids[i]]
// Single block, 1024 threads, fixed-trip predicated unroll (5115 <= 5*1024).
__global__ __launch_bounds__(1024) void build_coeff_kernel(
    const int* __restrict__ flat_idx,
    const int* __restrict__ seg_ids,
    const float* __restrict__ w_flat,
    const float* __restrict__ diag_w,
    const float* __restrict__ dense_W,
    float* __restrict__ coeff,
    int total)
{
    __shared__ float s_coeff[N_FEATURES];
    for (int i = threadIdx.x; i < N_FEATURES; i += 1024) s_coeff[i] = 0.0f;
    __syncthreads();
#pragma unroll
    for (int k = 0; k < 5; ++k) {
        const int i = k * 1024 + (int)threadIdx.x;
        const bool valid = (i < total);
        const int  idx = valid ? flat_idx[i] : 0;
        const int  g   = valid ? seg_ids[i]  : 0;
        const float wv = valid ? w_flat[i]   : 0.0f;
        const float c  = wv * diag_w[g] * dense_W[g];
        if (valid) atomicAdd(&s_coeff[idx], c);
    }
    for (int i = 5 * 1024 + (int)threadIdx.x; i < total; i += 1024) {  // robustness tail
        const int g = seg_ids[i];
        atomicAdd(&s_coeff[flat_idx[i]], w_flat[i] * diag_w[g] * dense_W[g]);
    }
    __syncthreads();
    for (int i = threadIdx.x; i < N_FEATURES; i += 1024) coeff[i] = s_coeff[i];
}

// Kernel 2: persistent-wave gemv, coeff register-resident, NT x loads.
// - Each wave preloads ALL of coeff into 16 float4 regs (lane l holds
//   coeff4[(k<<6)|l], matching the x layout) -> 16 VMEM instr per row
//   instead of 32: halves VMEM issue, the suspected post-NT limiter.
// - x loads NONTEMPORAL (round-6 verified +12us: streaming 134 MB must not
//   allocate in the poison-warmed L2/L3).
// - 512 blocks (2/CU, 8 waves/CU), 4 rows per wave as 2 interleaved pairs:
//   32 x-loads in flight per pass, two acc chains, few wave tails.
__global__ __launch_bounds__(256) void gemv_kernel(
    const float* __restrict__ x,
    const float* __restrict__ coeff,
    float* __restrict__ out)
{
    const int lane = threadIdx.x & 63;
    const int wid  = threadIdx.x >> 6;
    const int wave = (blockIdx.x << 2) | wid;   // 0..2047
    const int row0 = wave << 2;                 // 4 rows per wave

    const f32x4* __restrict__ c4 = (const f32x4*)coeff;
    f32x4 c[16];
#pragma unroll
    for (int k = 0; k < 16; ++k) c[k] = c4[(k << 6) | lane];   // cached, one-time

#pragma unroll
    for (int p = 0; p < 2; ++p) {
        const int rA = row0 + (p << 1);
        const int rB = rA + 1;
        const f32x4* __restrict__ xA = (const f32x4*)(x + (size_t)rA * N_FEATURES);
        const f32x4* __restrict__ xB = (const f32x4*)(x + (size_t)rB * N_FEATURES);

        float accA = 0.0f, accB = 0.0f;
#pragma unroll
        for (int k = 0; k < 16; ++k) {
            const int i = (k << 6) | lane;
            const f32x4 a = __builtin_nontemporal_load(&xA[i]);
            const f32x4 b = __builtin_nontemporal_load(&xB[i]);
            accA += a.x * c[k].x + a.y * c[k].y + a.z * c[k].z + a.w * c[k].w;
            accB += b.x * c[k].x + b.y * c[k].y + b.z * c[k].z + b.w * c[k].w;
        }

#pragma unroll
        for (int off = 32; off > 0; off >>= 1) {
            accA += __shfl_down(accA, off, 64);
            accB += __shfl_down(accB, off, 64);
        }
        if (lane == 0) {
            out[rA] = accA;
            out[rB] = accB;
        }
    }
}

extern "C" void kernel_launch(void* const* d_in, const int* in_sizes, int n_in,
                              void* d_out, int out_size, void* d_ws, size_t ws_size,
                              hipStream_t stream) {
    const float* x        = (const float*)d_in[0];  // [BATCH, N_FEATURES]
    const int*   flat_idx = (const int*)d_in[1];    // [total]
    const int*   seg_ids  = (const int*)d_in[2];    // [total]
    const float* w_flat   = (const float*)d_in[3];  // [total]
    const float* diag_w   = (const float*)d_in[4];  // [N_GROUPS]
    const float* dense_W  = (const float*)d_in[5];  // [N_GROUPS]
    float* out = (float*)d_out;                     // [BATCH] (shape [BATCH,1])
    const int total = in_sizes[1];

    float* coeff = (float*)d_ws;  // N_FEATURES floats

    build_coeff_kernel<<<1, 1024, 0, stream>>>(flat_idx, seg_ids, w_flat,
                                               diag_w, dense_W, coeff, total);
    gemv_kernel<<<512, 256, 0, stream>>>(x, coeff, out);
}

// Round 10
// 197.515 us; speedup vs baseline: 1.4446x; 1.0136x over previous
//
#include <hip/hip_runtime.h>

#define N_FEATURES 4096
#define N_GROUPS   1024
#define BATCH      8192

typedef float f32x4 __attribute__((ext_vector_type(4)));

// Kernel 1: coeff[f] = sum_{i: flat_idx[i]==f} w_flat[i]*diag_w[seg_ids[i]]*dense_W[seg_ids[i]]
// Single block, 1024 threads, fixed-trip predicated unroll (total=5115 <= 5*1024):
// all gather loads issue up front, LDS atomics drain with latency hidden.
__global__ __launch_bounds__(1024) void build_coeff_kernel(
    const int* __restrict__ flat_idx,
    const int* __restrict__ seg_ids,
    const float* __restrict__ w_flat,
    const float* __restrict__ diag_w,
    const float* __restrict__ dense_W,
    float* __restrict__ coeff,
    int total)
{
    __shared__ float s_coeff[N_FEATURES];
    for (int i = threadIdx.x; i < N_FEATURES; i += 1024) s_coeff[i] = 0.0f;
    __syncthreads();

#pragma unroll
    for (int k = 0; k < 5; ++k) {
        const int i = k * 1024 + (int)threadIdx.x;
        const bool valid = (i < total);
        const int  idx = valid ? flat_idx[i] : 0;
        const int  g   = valid ? seg_ids[i]  : 0;
        const float wv = valid ? w_flat[i]   : 0.0f;
        const float c  = wv * diag_w[g] * dense_W[g];
        if (valid) atomicAdd(&s_coeff[idx], c);
    }
    for (int i = 5 * 1024 + (int)threadIdx.x; i < total; i += 1024) {  // robustness tail
        const int g = seg_ids[i];
        atomicAdd(&s_coeff[flat_idx[i]], w_flat[i] * diag_w[g] * dense_W[g]);
    }
    __syncthreads();
    for (int i = threadIdx.x; i < N_FEATURES; i += 1024) coeff[i] = s_coeff[i];
}

// Kernel 2 (verified best, round 6): out[b] = dot(x[b,:], coeff).
// One wave per row, 64 lanes x 16 float4, wave-only shuffle reduce.
// x loaded NONTEMPORAL (verified +12us: the streaming 134 MB must not
// allocate in the poison-warmed L2/L3); coeff cached (16 KB, reused by all
// 2048 blocks). 2048 blocks x 4 waves = 32 waves/CU.
__global__ __launch_bounds__(256) void gemv_kernel(
    const float* __restrict__ x,
    const float* __restrict__ coeff,
    float* __restrict__ out)
{
    const int wid  = threadIdx.x >> 6;                 // wave id in block: 0..3
    const int lane = threadIdx.x & 63;
    const int row  = (blockIdx.x << 2) | wid;          // one row per wave

    const f32x4* __restrict__ xr = (const f32x4*)(x + (size_t)row * N_FEATURES);
    const f32x4* __restrict__ c4 = (const f32x4*)coeff;

    float acc = 0.0f;
#pragma unroll
    for (int k = 0; k < 16; ++k) {
        const int i = (k << 6) | lane;                 // coalesced 1 KiB/wave/instr
        const f32x4 xv = __builtin_nontemporal_load(&xr[i]);
        const f32x4 cv = c4[i];                        // cached: 16 KB, reused everywhere
        acc += xv.x * cv.x + xv.y * cv.y + xv.z * cv.z + xv.w * cv.w;
    }

#pragma unroll
    for (int off = 32; off > 0; off >>= 1)
        acc += __shfl_down(acc, off, 64);

    if (lane == 0) out[row] = acc;
}

extern "C" void kernel_launch(void* const* d_in, const int* in_sizes, int n_in,
                              void* d_out, int out_size, void* d_ws, size_t ws_size,
                              hipStream_t stream) {
    const float* x        = (const float*)d_in[0];  // [BATCH, N_FEATURES]
    const int*   flat_idx = (const int*)d_in[1];    // [total]
    const int*   seg_ids  = (const int*)d_in[2];    // [total]
    const float* w_flat   = (const float*)d_in[3];  // [total]
    const float* diag_w   = (const float*)d_in[4];  // [N_GROUPS]
    const float* dense_W  = (const float*)d_in[5];  // [N_GROUPS]
    float* out = (float*)d_out;                     // [BATCH] (shape [BATCH,1])
    const int total = in_sizes[1];

    float* coeff = (float*)d_ws;  // N_FEATURES floats

    build_coeff_kernel<<<1, 1024, 0, stream>>>(flat_idx, seg_ids, w_flat,
                                               diag_w, dense_W, coeff, total);
    gemv_kernel<<<BATCH / 4, 256, 0, stream>>>(x, coeff, out);
}